// Round 10
// baseline (7005.569 us; speedup 1.0000x reference)
//
#include <hip/hip_runtime.h>
#include <math.h>

// NeuroRNN: I = 0.8 I + 0.2 (Wrec r + Win x_t); r = 0.9 r + 0.1 tanh(I); out = Wout r
// B=32, T=2048, IN=256, H=1024, OUT=128 (all fp32)
//
// Persistent kernel, 256 WGs x 256 thr. 100 KB *used* static LDS -> 1 WG/CU
// (capacity-forced) -> exactly 32 WGs per XCD. WGs self-organize by physical
// XCD (HW_REG_XCC_ID, validated R5): bg = xcc (batches [4bg,4bg+4)),
// jb = atomic rank in XCD (h-rows [32jb,+32)).
//
// Compute (R9, proven): waves 0,1 do Wrec*r via mfma_f32_16x16x32_bf16 with
// static bf16 A-frags in VGPRs; wave 2 does Wout*r; Win*x_{t+1} computed by all
// waves in the shadow phase (fp32 + shuffle reduce) into double-buffered LDS.
//
// Exchange (NEW): tagged bf16 r data, DUAL-PUBLISHED:
//   fast buffer: plain stores -> dirty in producer's own XCD L2; consumers
//     (same XCD by construction) poll with sc0 loads. Stale-line safety: a
//     stale L1/L2 line can only hold the previous use of the slot (2 steps
//     old) whose tag always mismatches -> never accepted, only demotion.
//   slow buffer: sc0 sc1 stores/loads via MALL (R7-R9 proven correct).
// Consumers try fast <=16 iters (256 during startup), then stickily demote to
// slow. Bounded spin -> no deadlock possible. r_lds double-buffered -> ONE
// barrier per step.

#define T_STEPS 2048
#define B_SZ 32
#define IN_SZ 256
#define H_SZ 1024
#define OUT_SZ 128
#define WGS 256
#define NWG 256
#define PB_WORDS (B_SZ * (H_SZ / 2))   // one buffer: 16384 u32 (bf16 pairs)
#define FAST_OFF (2 * PB_WORDS)        // fast double-buffer starts here
#define CNT_OFF  (4 * PB_WORDS)        // per-XCD rank counters (8 x 16 u32)
#define WS_WORDS (4 * PB_WORDS + 128)

typedef unsigned int u32;
typedef u32 u32x2 __attribute__((ext_vector_type(2)));
typedef u32 u32x4 __attribute__((ext_vector_type(4)));
typedef float f32x4 __attribute__((ext_vector_type(4)));
typedef short s16x8 __attribute__((ext_vector_type(8)));

// init: r buffers (slow+fast) to tag=1/value~0; rank counters to 0.
// Dispatch-boundary cache flush makes this coherent for the main kernel.
__global__ void nrnn_init_ws(u32* __restrict__ ws) {
  const int i = blockIdx.x * blockDim.x + threadIdx.x;
  if (i < CNT_OFF) ws[i] = 0x00000001u;
  else if (i < WS_WORDS) ws[i] = 0u;
}

__device__ __forceinline__ u32 bf16r(float x) {  // round-to-nearest-even bf16
  const u32 b = __float_as_uint(x);
  return (b + 0x7FFFu + ((b >> 16) & 1u)) >> 16;
}
__device__ __forceinline__ float tanh_fast(float x) {
  const float cx = fminf(fmaxf(x, -15.f), 15.f);
  const float e = __expf(2.f * cx);
  return (e - 1.f) * __builtin_amdgcn_rcpf(e + 1.f);
}

__global__ void __launch_bounds__(WGS, 1)
nrnn_main(const float* __restrict__ x, const float* __restrict__ Win,
          const float* __restrict__ Wrec, const float* __restrict__ Wout,
          float* __restrict__ out, float* __restrict__ ws) {
  const int tid = (int)threadIdx.x;
  const int hg  = tid >> 5;   // 0..7 : h sub-group for Win*x (4 rows each)
  const int s   = tid & 31;   // 0..31: k-slice lane for Win*x
  const int wv  = tid >> 6;   // wave id: 0,1 = Wrec-MFMA; 2 = Wout-MFMA; 3 = aux
  const int ln  = tid & 63;   // lane in wave

  // 100 KB single static LDS block (genuinely used -> not DCE'd -> 1 WG/CU).
  __shared__ __align__(16) char smem[102400];
  char* r_lds = smem;                                      // [2][8192] bf16 r, swizzled
  float (*wacc_lds)[32][4] = (float (*)[32][4])(smem + 16384);  // [2][32][4]
  __shared__ u32 s_role[2];

  // ---- self-organize by physical XCD (R5-proven) ----
  if (tid == 0) {
    u32 xcc;
    asm volatile("s_getreg_b32 %0, hwreg(HW_REG_XCC_ID)" : "=s"(xcc));
    xcc &= 7u;
    u32* xcnt = (u32*)ws + CNT_OFF;
    const u32 rank = atomicAdd(&xcnt[xcc * 16], 1u);
    s_role[0] = xcc;
    s_role[1] = rank & 31u;
  }
  __syncthreads();
  const int bg = (int)s_role[0];
  const int jb = (int)s_role[1];
  const int b0 = bg * 4;

  u32* slowb = (u32*)ws;
  u32* fastb = (u32*)ws + FAST_OFF;

  // ---- A-fragments -> VGPRs (static bf16 weights) ----
  s16x8 wfrag[32];
  {
    const int g = (ln >> 4) & 3;
    const float* wp;
    if (wv < 2)       wp = Wrec + (size_t)(jb * 32 + wv * 16 + (ln & 15)) * H_SZ;
    else if (wv == 2) wp = Wout + (size_t)(jb * 4 + (ln & 3)) * H_SZ;
    else              wp = Wrec;  // wave 3: content unused
    #pragma unroll
    for (int st = 0; st < 32; ++st) {
      const int k0 = st * 32 + g * 8;
      const float4 c0 = *(const float4*)(wp + k0);
      const float4 c1 = *(const float4*)(wp + k0 + 4);
      s16x8 w;
      w[0] = (short)bf16r(c0.x); w[1] = (short)bf16r(c0.y);
      w[2] = (short)bf16r(c0.z); w[3] = (short)bf16r(c0.w);
      w[4] = (short)bf16r(c1.x); w[5] = (short)bf16r(c1.y);
      w[6] = (short)bf16r(c1.z); w[7] = (short)bf16r(c1.w);
      wfrag[st] = w;
    }
  }

  // ---- Win slice -> registers (fp32) ----
  float4 wi4[4][2];
  #pragma unroll
  for (int hh = 0; hh < 4; ++hh) {
    const float* ip = Win + (size_t)(jb * 32 + hg * 4 + hh) * IN_SZ + s * 4;
    wi4[hh][0] = *(const float4*)(ip);
    wi4[hh][1] = *(const float4*)(ip + 128);
  }

  // ---- persistent state ----
  float Ist[4] = {0.f, 0.f, 0.f, 0.f};
  float rloc[4] = {0.f, 0.f, 0.f, 0.f};
  bool fastOK = true;

  // ---- prologue: Win*x_0 -> wacc_lds[0] ----
  {
    float wacc[4][4];
    #pragma unroll
    for (int b = 0; b < 4; ++b)
      #pragma unroll
      for (int hh = 0; hh < 4; ++hh) wacc[b][hh] = 0.f;
    #pragma unroll
    for (int b = 0; b < 4; ++b) {
      const float* xp = x + ((size_t)(b0 + b) * T_STEPS) * IN_SZ + s * 4;
      const float4 x0 = *(const float4*)(xp);
      const float4 x1 = *(const float4*)(xp + 128);
      #pragma unroll
      for (int hh = 0; hh < 4; ++hh) {
        float4 w4 = wi4[hh][0];
        wacc[b][hh] = fmaf(w4.x, x0.x, wacc[b][hh]);
        wacc[b][hh] = fmaf(w4.y, x0.y, wacc[b][hh]);
        wacc[b][hh] = fmaf(w4.z, x0.z, wacc[b][hh]);
        wacc[b][hh] = fmaf(w4.w, x0.w, wacc[b][hh]);
        w4 = wi4[hh][1];
        wacc[b][hh] = fmaf(w4.x, x1.x, wacc[b][hh]);
        wacc[b][hh] = fmaf(w4.y, x1.y, wacc[b][hh]);
        wacc[b][hh] = fmaf(w4.z, x1.z, wacc[b][hh]);
        wacc[b][hh] = fmaf(w4.w, x1.w, wacc[b][hh]);
      }
    }
    #pragma unroll
    for (int m = 1; m <= 16; m <<= 1)
      #pragma unroll
      for (int b = 0; b < 4; ++b)
        #pragma unroll
        for (int hh = 0; hh < 4; ++hh)
          wacc[b][hh] += __shfl_xor(wacc[b][hh], m, 64);
    if (s < 16) wacc_lds[0][hg * 4 + (s & 3)][s >> 2] = wacc[s >> 2][s & 3];
  }

  // poll + stage r_{tcur-1} into r_lds[tcur&1]; fast (own-XCD L2) with sticky
  // demotion to slow (MALL). Tag mismatch on stale lines -> never accepted.
  auto poll_stage = [&](int tcur) {
    const u32 etag = (((u32)(tcur - 1)) >> 1) & 1u;
    const size_t boff = (size_t)((tcur + 1) & 1) * PB_WORDS + (size_t)bg * 2048u;
    const u32* fp0 = fastb + boff + 4 * tid;
    const u32* fp1 = fastb + boff + 1024 + 4 * tid;
    const u32* sp0 = slowb + boff + 4 * tid;
    const u32* sp1 = slowb + boff + 1024 + 4 * tid;
    u32x4 a0, a1;
    bool got = false;
    if (fastOK) {
      int tries = (tcur < 4) ? 256 : 16;
      while (tries-- > 0) {
        asm volatile(
            "global_load_dwordx4 %0, %2, off sc0\n\t"
            "global_load_dwordx4 %1, %3, off sc0\n\t"
            "s_waitcnt vmcnt(0)"
            : "=&v"(a0), "=&v"(a1) : "v"(fp0), "v"(fp1) : "memory");
        u32 bad = 0;
        #pragma unroll
        for (int i = 0; i < 4; ++i) { bad |= a0[i] ^ etag; bad |= a1[i] ^ etag; }
        const bool ok = ((bad & 1u) == 0u);
        if (__all(ok)) { got = true; break; }
      }
      if (!got) fastOK = false;  // sticky demotion (perf-only decision)
    }
    if (!got) {
      bool ok;
      do {
        asm volatile(
            "global_load_dwordx4 %0, %2, off sc0 sc1\n\t"
            "global_load_dwordx4 %1, %3, off sc0 sc1\n\t"
            "s_waitcnt vmcnt(0)"
            : "=&v"(a0), "=&v"(a1) : "v"(sp0), "v"(sp1) : "memory");
        u32 bad = 0;
        #pragma unroll
        for (int i = 0; i < 4; ++i) { bad |= a0[i] ^ etag; bad |= a1[i] ^ etag; }
        ok = ((bad & 1u) == 0u);
      } while (__any(!ok));
    }
    char* dst = r_lds + (size_t)(tcur & 1) * 8192;
    const int bi0 = tid >> 7, bi1 = 2 + (tid >> 7);
    *(u32x4*)(dst + ((16 * tid) ^ ((bi0 & 3) << 4) ^ ((bi0 & 1) << 6))) = a0;
    *(u32x4*)(dst + ((4096 + 16 * tid) ^ ((bi1 & 3) << 4) ^ ((bi1 & 1) << 6))) = a1;
  };

  for (int t = 0; t < T_STEPS; ++t) {
    // ---- prefetch x_{t+1} (consumed in shadow phase) ----
    const int tt = (t + 1 < T_STEPS) ? (t + 1) : (T_STEPS - 1);
    float4 xv[4][2];
    #pragma unroll
    for (int b = 0; b < 4; ++b) {
      const float* xp = x + ((size_t)(b0 + b) * T_STEPS + (size_t)tt) * IN_SZ + s * 4;
      xv[b][0] = *(const float4*)(xp);
      xv[b][1] = *(const float4*)(xp + 128);
    }

    poll_stage(t);
    __syncthreads();  // the ONLY barrier per step: r_lds[t&1] + wacc_lds[t&1] ready

    // ---- MFMA chains (waves 0..2) over K=1024 ----
    f32x4 acc = {0.f, 0.f, 0.f, 0.f};
    if (wv <= 2) {
      const int beff = ln & 3;
      const int g16 = ((ln >> 4) & 3) * 16;
      const int bswz = ((beff & 3) << 4) | ((beff & 1) << 6);
      const char* rb = r_lds + (size_t)(t & 1) * 8192 + beff * 2048;
      #pragma unroll
      for (int st = 0; st < 32; ++st) {
        const s16x8 bf = *(const s16x8*)(rb + ((st * 64 + g16) ^ bswz));
        acc = __builtin_amdgcn_mfma_f32_16x16x32_bf16(wfrag[st], bf, acc, 0, 0, 0);
      }
    }

    // ---- waves 0,1: I-update, fast tanh, dual tagged bf16 publish ----
    if (wv < 2 && (ln & 12) == 0) {
      const int b = ln & 3;
      const int g = ln >> 4;
      const int rbase = wv * 16 + g * 4;
      const u32 ptag = (((u32)t) >> 1) & 1u;
      float In0 = fmaf(0.2f, acc[0] + wacc_lds[t & 1][rbase + 0][b], 0.8f * Ist[0]);
      float In1 = fmaf(0.2f, acc[1] + wacc_lds[t & 1][rbase + 1][b], 0.8f * Ist[1]);
      float In2 = fmaf(0.2f, acc[2] + wacc_lds[t & 1][rbase + 2][b], 0.8f * Ist[2]);
      float In3 = fmaf(0.2f, acc[3] + wacc_lds[t & 1][rbase + 3][b], 0.8f * Ist[3]);
      Ist[0] = In0; Ist[1] = In1; Ist[2] = In2; Ist[3] = In3;
      rloc[0] = fmaf(0.1f, tanh_fast(In0), 0.9f * rloc[0]);
      rloc[1] = fmaf(0.1f, tanh_fast(In1), 0.9f * rloc[1]);
      rloc[2] = fmaf(0.1f, tanh_fast(In2), 0.9f * rloc[2]);
      rloc[3] = fmaf(0.1f, tanh_fast(In3), 0.9f * rloc[3]);
      u32x2 pk;
      pk[0] = (((bf16r(rloc[1]) << 16) | (bf16r(rloc[0]) & 0xFFFFu)) & ~1u) | ptag;
      pk[1] = (((bf16r(rloc[3]) << 16) | (bf16r(rloc[2]) & 0xFFFFu)) & ~1u) | ptag;
      const size_t po = (size_t)(t & 1) * PB_WORDS
                        + (size_t)(b0 + b) * 512 + jb * 16 + wv * 8 + g * 2;
      u32* pwF = fastb + po;
      u32* pwS = slowb + po;
      asm volatile("global_store_dwordx2 %0, %1, off" :: "v"(pwF), "v"(pk) : "memory");
      asm volatile("global_store_dwordx2 %0, %1, off sc0 sc1" :: "v"(pwS), "v"(pk) : "memory");
    }

    // ---- wave 2: out_{t-1} = Wout r_{t-1} ----
    if (wv == 2 && ln < 4 && t > 0) {
      #pragma unroll
      for (int reg = 0; reg < 4; ++reg)
        out[((size_t)(b0 + ln) * T_STEPS + (size_t)(t - 1)) * OUT_SZ + jb * 4 + reg] = acc[reg];
    }

    // ---- shadow (all waves): Win*x_{t+1} -> wacc_lds[(t+1)&1] ----
    {
      float wacc[4][4];
      #pragma unroll
      for (int b = 0; b < 4; ++b)
        #pragma unroll
        for (int hh = 0; hh < 4; ++hh) wacc[b][hh] = 0.f;
      #pragma unroll
      for (int b = 0; b < 4; ++b) {
        const float4 x0 = xv[b][0];
        const float4 x1 = xv[b][1];
        #pragma unroll
        for (int hh = 0; hh < 4; ++hh) {
          float4 w4 = wi4[hh][0];
          wacc[b][hh] = fmaf(w4.x, x0.x, wacc[b][hh]);
          wacc[b][hh] = fmaf(w4.y, x0.y, wacc[b][hh]);
          wacc[b][hh] = fmaf(w4.z, x0.z, wacc[b][hh]);
          wacc[b][hh] = fmaf(w4.w, x0.w, wacc[b][hh]);
          w4 = wi4[hh][1];
          wacc[b][hh] = fmaf(w4.x, x1.x, wacc[b][hh]);
          wacc[b][hh] = fmaf(w4.y, x1.y, wacc[b][hh]);
          wacc[b][hh] = fmaf(w4.z, x1.z, wacc[b][hh]);
          wacc[b][hh] = fmaf(w4.w, x1.w, wacc[b][hh]);
        }
      }
      #pragma unroll
      for (int m = 1; m <= 16; m <<= 1)
        #pragma unroll
        for (int b = 0; b < 4; ++b)
          #pragma unroll
          for (int hh = 0; hh < 4; ++hh)
            wacc[b][hh] += __shfl_xor(wacc[b][hh], m, 64);
      if (s < 16)
        wacc_lds[(t + 1) & 1][hg * 4 + (s & 3)][s >> 2] = wacc[s >> 2][s & 3];
    }
    // no second barrier: r_lds is double-buffered; wacc_lds[(t+1)&1] is fenced
    // by the next iteration's barrier before anyone reads it.
  }

  // ---- epilogue: out for t = T-1 ----
  poll_stage(T_STEPS);
  __syncthreads();
  {
    f32x4 acc = {0.f, 0.f, 0.f, 0.f};
    if (wv == 2) {
      const int beff = ln & 3;
      const int g16 = ((ln >> 4) & 3) * 16;
      const int bswz = ((beff & 3) << 4) | ((beff & 1) << 6);
      const char* rb = r_lds + (size_t)(T_STEPS & 1) * 8192 + beff * 2048;
      #pragma unroll
      for (int st = 0; st < 32; ++st) {
        const s16x8 bf = *(const s16x8*)(rb + ((st * 64 + g16) ^ bswz));
        acc = __builtin_amdgcn_mfma_f32_16x16x32_bf16(wfrag[st], bf, acc, 0, 0, 0);
      }
      if (ln < 4) {
        #pragma unroll
        for (int reg = 0; reg < 4; ++reg)
          out[((size_t)(b0 + ln) * T_STEPS + (size_t)(T_STEPS - 1)) * OUT_SZ + jb * 4 + reg] = acc[reg];
      }
    }
  }
}

extern "C" void kernel_launch(void* const* d_in, const int* in_sizes, int n_in,
                              void* d_out, int out_size, void* d_ws, size_t ws_size,
                              hipStream_t stream) {
  const float* xp    = (const float*)d_in[0];
  const float* winp  = (const float*)d_in[1];
  const float* wrecp = (const float*)d_in[2];
  const float* woutp = (const float*)d_in[3];
  float* outp = (float*)d_out;
  float* wsp  = (float*)d_ws;

  // re-init both r buffer sets + rank counters every call (graph-replay safe;
  // dispatch-boundary cache flush makes it coherent for nrnn_main)
  nrnn_init_ws<<<(WS_WORDS + 255) / 256, 256, 0, stream>>>((u32*)d_ws);

  nrnn_main<<<dim3(NWG), dim3(WGS), 0, stream>>>(xp, winp, wrecp, woutp, outp, wsp);
}